// Round 1
// baseline (2714.594 us; speedup 1.0000x reference)
//
#include <hip/hip_runtime.h>
#include <math.h>

#define B 128
#define L 2048
#define H 512
#define D 512
#define NG 2048   // 4*H
#define T 10
#define S 8       // L-chunks per batch row for attention partials

// workspace layout (float offsets)
#define OFF_S     ((size_t)0)                    // current s (= c_{t-1}), B*H
#define OFF_H     ((size_t)65536)                // hidden h, B*H
#define OFF_X     ((size_t)131072)               // current x, B*D
#define OFF_SNEW  ((size_t)196608)               // s + context, B*H
#define OFF_SS    ((size_t)262144)               // ||s||^2 per b, B
#define OFF_G     ((size_t)262272)               // gates, B*NG
#define OFF_PM    ((size_t)524416)               // partial m, B*S
#define OFF_PL    ((size_t)525440)               // partial l, B*S
#define OFF_PCTX  ((size_t)526464)               // partial ctx, B*S*H

__device__ __forceinline__ float sigf(float x){ return 1.0f / (1.0f + __expf(-x)); }

__device__ __forceinline__ float block_sum256(float v){
    for (int off = 32; off; off >>= 1) v += __shfl_xor(v, off, 64);
    __shared__ float r[4];
    int wave = threadIdx.x >> 6, lane = threadIdx.x & 63;
    if (lane == 0) r[wave] = v;
    __syncthreads();
    return r[0] + r[1] + r[2] + r[3];
}

// ---- init: s=s0, h=h0, x=batch, ss=||s0||^2 ----
__global__ void init_k(const float* __restrict__ s0, const float* __restrict__ h0,
                       const float* __restrict__ x0, float* __restrict__ ws){
    int b = blockIdx.x, t = threadIdx.x;
    float ssq = 0.f;
    for (int h = t; h < H; h += 256){
        float sv = s0[b*H + h];
        ws[OFF_S + b*H + h] = sv;
        ws[OFF_H + b*H + h] = h0[b*H + h];
        ssq += sv * sv;
    }
    for (int d = t; d < D; d += 256) ws[OFF_X + b*D + d] = x0[b*D + d];
    float tot = block_sum256(ssq);
    if (t == 0) ws[OFF_SS + b] = tot;
}

// ---- attention partials: one pass over hid_states chunk with online softmax ----
__global__ __launch_bounds__(256) void attn_part(const float* __restrict__ hid,
                                                 float* __restrict__ ws){
    int bid = blockIdx.x;
    int b = bid >> 3, chunk = bid & (S - 1);
    int wave = threadIdx.x >> 6, lane = threadIdx.x & 63;

    const float* sb = ws + OFF_S + (size_t)b * H;
    float ssb = ws[OFF_SS + b];
    float4 s4a = *(const float4*)(sb + 4*lane);
    float4 s4b = *(const float4*)(sb + 256 + 4*lane);

    float m = -1e30f, l = 0.f;
    float4 c4a = {0,0,0,0}, c4b = {0,0,0,0};

    int l0 = chunk * 256 + wave * 64;
    const float* hbase = hid + ((size_t)b * L + l0) * H;

    for (int i = 0; i < 64; i++){
        const float* hrow = hbase + (size_t)i * H;
        float4 v4a = *(const float4*)(hrow + 4*lane);
        float4 v4b = *(const float4*)(hrow + 256 + 4*lane);
        float dot = v4a.x*s4a.x + v4a.y*s4a.y + v4a.z*s4a.z + v4a.w*s4a.w
                  + v4b.x*s4b.x + v4b.y*s4b.y + v4b.z*s4b.z + v4b.w*s4b.w;
        float sq  = v4a.x*v4a.x + v4a.y*v4a.y + v4a.z*v4a.z + v4a.w*v4a.w
                  + v4b.x*v4b.x + v4b.y*v4b.y + v4b.z*v4b.z + v4b.w*v4b.w;
        for (int off = 32; off; off >>= 1){
            dot += __shfl_xor(dot, off, 64);
            sq  += __shfl_xor(sq,  off, 64);
        }
        float score = dot / (sqrtf(sq * ssb) + 1e-8f);
        float nm = fmaxf(m, score);
        float alpha = __expf(m - nm);
        float p = __expf(score - nm);
        l = l * alpha + p;
        c4a.x = c4a.x*alpha + p*v4a.x;  c4a.y = c4a.y*alpha + p*v4a.y;
        c4a.z = c4a.z*alpha + p*v4a.z;  c4a.w = c4a.w*alpha + p*v4a.w;
        c4b.x = c4b.x*alpha + p*v4b.x;  c4b.y = c4b.y*alpha + p*v4b.y;
        c4b.z = c4b.z*alpha + p*v4b.z;  c4b.w = c4b.w*alpha + p*v4b.w;
        m = nm;
    }

    // combine 4 waves in block
    __shared__ float lm[4], ll[4];
    __shared__ float lctx[4][512];
    *(float4*)&lctx[wave][4*lane]       = c4a;
    *(float4*)&lctx[wave][256 + 4*lane] = c4b;
    if (lane == 0){ lm[wave] = m; ll[wave] = l; }
    __syncthreads();

    float M = fmaxf(fmaxf(lm[0], lm[1]), fmaxf(lm[2], lm[3]));
    float e0 = __expf(lm[0]-M), e1 = __expf(lm[1]-M);
    float e2 = __expf(lm[2]-M), e3 = __expf(lm[3]-M);
    int t = threadIdx.x;
    float* pc = ws + OFF_PCTX + ((size_t)b * S + chunk) * H;
    pc[t]       = lctx[0][t]*e0     + lctx[1][t]*e1     + lctx[2][t]*e2     + lctx[3][t]*e3;
    pc[t + 256] = lctx[0][t+256]*e0 + lctx[1][t+256]*e1 + lctx[2][t+256]*e2 + lctx[3][t+256]*e3;
    if (t == 0){
        ws[OFF_PM + b*S + chunk] = M;
        ws[OFF_PL + b*S + chunk] = ll[0]*e0 + ll[1]*e1 + ll[2]*e2 + ll[3]*e3;
    }
}

// ---- combine partials: snew = s + context ----
__global__ void attn_comb(float* __restrict__ ws){
    int b = blockIdx.x, t = threadIdx.x;
    float ms[S], e[S];
    float M = -1e30f;
    for (int i = 0; i < S; i++){ ms[i] = ws[OFF_PM + b*S + i]; M = fmaxf(M, ms[i]); }
    float Lsum = 0.f;
    for (int i = 0; i < S; i++){ e[i] = __expf(ms[i] - M); Lsum += ws[OFF_PL + b*S + i] * e[i]; }
    float inv = 1.0f / Lsum;
    for (int h = t; h < H; h += 256){
        float c = 0.f;
        for (int i = 0; i < S; i++) c += ws[OFF_PCTX + ((size_t)b*S + i)*H + h] * e[i];
        ws[OFF_SNEW + b*H + h] = ws[OFF_S + b*H + h] + c * inv;
    }
}

// ---- gates = x @ W_ih + h @ W_hh + b ----
__global__ __launch_bounds__(256) void gates_k(const float* __restrict__ Wih,
                                               const float* __restrict__ Whh,
                                               const float* __restrict__ bias,
                                               float* __restrict__ ws){
    __shared__ float xs[8][512];
    __shared__ float hsh[8][512];
    int tid = threadIdx.x;
    int b0 = blockIdx.y * 8, n0 = blockIdx.x * 128;
    for (int i = tid; i < 1024; i += 256){
        int r = i >> 7, c = (i & 127) << 2;
        *(float4*)&xs[r][c]  = *(const float4*)(ws + OFF_X + (size_t)(b0 + r)*D + c);
        *(float4*)&hsh[r][c] = *(const float4*)(ws + OFF_H + (size_t)(b0 + r)*H + c);
    }
    __syncthreads();
    int nt = tid & 31, bi = tid >> 5;
    int n = n0 + nt * 4;
    float4 acc = { bias[n], bias[n+1], bias[n+2], bias[n+3] };
    for (int k = 0; k < 512; k++){
        float xv = xs[bi][k], hv = hsh[bi][k];
        float4 w1 = *(const float4*)(Wih + (size_t)k*NG + n);
        float4 w2 = *(const float4*)(Whh + (size_t)k*NG + n);
        acc.x += xv*w1.x + hv*w2.x;
        acc.y += xv*w1.y + hv*w2.y;
        acc.z += xv*w1.z + hv*w2.z;
        acc.w += xv*w1.w + hv*w2.w;
    }
    *(float4*)(ws + OFF_G + (size_t)(b0 + bi)*NG + n) = acc;
}

// ---- LSTM cell: c = sig(f)*snew + sig(i)*tanh(g); h = sig(o)*tanh(c); ss=||c||^2 ----
__global__ void cell_k(float* __restrict__ ws){
    int b = blockIdx.x, t = threadIdx.x;
    const float* g = ws + OFF_G + (size_t)b * NG;
    float csq = 0.f;
    for (int h = t; h < H; h += 256){
        float gi = g[h], gf = g[512 + h], gg = g[1024 + h], go = g[1536 + h];
        float sn = ws[OFF_SNEW + b*H + h];
        float c  = sigf(gf) * sn + sigf(gi) * tanhf(gg);
        float hv = sigf(go) * tanhf(c);
        ws[OFF_S + b*H + h] = c;      // next step's attention query
        ws[OFF_H + b*H + h] = hv;
        csq += c * c;
    }
    float tot = block_sum256(csq);
    if (t == 0) ws[OFF_SS + b] = tot;
}

// ---- MLP head: x = leaky_relu(h@W1+b1) @ W2 + b2 ; scatter into out ----
__global__ void mlp_k(const float* __restrict__ W1, const float* __restrict__ b1,
                      const float* __restrict__ W2, const float* __restrict__ b2,
                      float* __restrict__ ws, float* __restrict__ out, int st){
    __shared__ float hl[512];
    __shared__ float part[4][64];
    __shared__ float t1[64];
    int b = blockIdx.x, t = threadIdx.x;
    for (int i = t; i < 128; i += 256)
        *(float4*)&hl[i*4] = *(const float4*)(ws + OFF_H + (size_t)b*H + i*4);
    __syncthreads();
    int j = t & 63, q = t >> 6;
    float a = 0.f;
    for (int k = q*128; k < q*128 + 128; k++) a += hl[k] * W1[k*64 + j];
    part[q][j] = a;
    __syncthreads();
    if (t < 64){
        float v = part[0][t] + part[1][t] + part[2][t] + part[3][t] + b1[t];
        t1[t] = v > 0.f ? v : 0.01f * v;
    }
    __syncthreads();
    for (int d = t; d < D; d += 256){
        float a2 = b2[d];
        for (int k = 0; k < 64; k++) a2 += t1[k] * W2[k*512 + d];
        ws[OFF_X + (size_t)b*D + d] = a2;
        int idx = st * D + d;                     // flat position within (D*T) per batch
        out[(size_t)b * (D*T) + (size_t)(idx % T) * D + (idx / T)] = a2;
    }
}

extern "C" void kernel_launch(void* const* d_in, const int* in_sizes, int n_in,
                              void* d_out, int out_size, void* d_ws, size_t ws_size,
                              hipStream_t stream) {
    const float* batch = (const float*)d_in[0];
    const float* hid   = (const float*)d_in[1];
    const float* h0    = (const float*)d_in[2];
    const float* s0    = (const float*)d_in[3];
    const float* Wih   = (const float*)d_in[4];
    const float* Whh   = (const float*)d_in[5];
    const float* bl    = (const float*)d_in[6];
    const float* W1    = (const float*)d_in[7];
    const float* b1    = (const float*)d_in[8];
    const float* W2    = (const float*)d_in[9];
    const float* b2    = (const float*)d_in[10];
    float* out = (float*)d_out;
    float* ws  = (float*)d_ws;

    init_k<<<B, 256, 0, stream>>>(s0, h0, batch, ws);
    for (int st = 0; st < T; st++){
        attn_part<<<B*S, 256, 0, stream>>>(hid, ws);
        attn_comb<<<B, 256, 0, stream>>>(ws);
        gates_k<<<dim3(16, 16), 256, 0, stream>>>(Wih, Whh, bl, ws);
        cell_k<<<B, 256, 0, stream>>>(ws);
        mlp_k<<<B, 256, 0, stream>>>(W1, b1, W2, b2, ws, out, st);
    }
}

// Round 2
// 2095.370 us; speedup vs baseline: 1.2955x; 1.2955x over previous
//
#include <hip/hip_runtime.h>
#include <math.h>

#define B 128
#define L 2048
#define H 512
#define D 512
#define NG 2048   // 4*H
#define T 10
#define S 16      // L-chunks per batch row for attention partials

// workspace layout (float offsets); ws_size = 2 GiB, we use ~276 MB
#define OFF_S    ((size_t)0)        // c state (attention query), B*H
#define OFF_H    ((size_t)65536)    // hidden h, B*H
#define OFF_X    ((size_t)131072)   // current x, B*D
#define OFF_SS   ((size_t)196608)   // ||s||^2 per b, B
#define OFF_G    ((size_t)196736)   // gates, B*NG
#define OFF_PM   ((size_t)458880)   // partial m, B*S
#define OFF_PL   ((size_t)460928)   // partial l, B*S
#define OFF_PCTX ((size_t)462976)   // partial ctx, B*S*H
#define OFF_RN   ((size_t)1511552)  // 1/||h_l||, B*L
#define OFF_HB   ((size_t)1773696)  // bf16 copy of hid_states, B*L*H bf16 (16B-aligned)

__device__ __forceinline__ float sigf(float x){ return 1.0f / (1.0f + __expf(-x)); }

__device__ __forceinline__ unsigned int b16r(float f){   // fp32 -> bf16 bits, RNE
    unsigned int u = __float_as_uint(f);
    return (u + 0x7FFFu + ((u >> 16) & 1u)) >> 16;
}
__device__ __forceinline__ unsigned int pack2(float lo, float hi){
    return b16r(lo) | (b16r(hi) << 16);
}

__device__ __forceinline__ float block_sum256(float v){
    for (int off = 32; off; off >>= 1) v += __shfl_xor(v, off, 64);
    __shared__ float r[4];
    int wave = threadIdx.x >> 6, lane = threadIdx.x & 63;
    if (lane == 0) r[wave] = v;
    __syncthreads();
    return r[0] + r[1] + r[2] + r[3];
}

// ---- init: s=s0, h=h0, x=batch, ss=||s0||^2 ----
__global__ void init_k(const float* __restrict__ s0, const float* __restrict__ h0,
                       const float* __restrict__ x0, float* __restrict__ ws){
    int b = blockIdx.x, t = threadIdx.x;
    float ssq = 0.f;
    for (int h = t; h < H; h += 256){
        float sv = s0[b*H + h];
        ws[OFF_S + b*H + h] = sv;
        ws[OFF_H + b*H + h] = h0[b*H + h];
        ssq += sv * sv;
    }
    for (int d = t; d < D; d += 256) ws[OFF_X + b*D + d] = x0[b*D + d];
    float tot = block_sum256(ssq);
    if (t == 0) ws[OFF_SS + b] = tot;
}

// ---- one-time: hid -> bf16, plus rn = 1/||h_l|| (fp32 accurate) ----
__global__ __launch_bounds__(256) void conv_k(const float* __restrict__ hid,
                                              float* __restrict__ ws){
    int row  = blockIdx.x * 4 + (threadIdx.x >> 6);   // one wave per L-row
    int lane = threadIdx.x & 63;
    const float* src = hid + (size_t)row * H + lane * 8;
    float4 a = *(const float4*)src;
    float4 c = *(const float4*)(src + 4);
    float sq = a.x*a.x + a.y*a.y + a.z*a.z + a.w*a.w
             + c.x*c.x + c.y*c.y + c.z*c.z + c.w*c.w;
    for (int off = 32; off; off >>= 1) sq += __shfl_xor(sq, off, 64);
    uint4 o;
    o.x = pack2(a.x, a.y); o.y = pack2(a.z, a.w);
    o.z = pack2(c.x, c.y); o.w = pack2(c.z, c.w);
    ((uint4*)(ws + OFF_HB))[(size_t)row * 64 + lane] = o;
    if (lane == 0) ws[OFF_RN + row] = rsqrtf(sq);
}

// ---- attention partials: single pass over bf16 hid with online softmax ----
__global__ __launch_bounds__(256) void attn_part(float* __restrict__ ws){
    int bid = blockIdx.x;
    int b = bid >> 4, chunk = bid & (S - 1);
    int wave = threadIdx.x >> 6, lane = threadIdx.x & 63;

    const float* sb = ws + OFF_S + (size_t)b * H + lane * 8;
    float4 s4a = *(const float4*)sb;
    float4 s4b = *(const float4*)(sb + 4);
    float rssb = rsqrtf(ws[OFF_SS + b]);

    int l0 = chunk * 128 + wave * 32;
    float rnv = (lane < 32) ? ws[OFF_RN + b * L + l0 + lane] : 0.f;
    const uint4* hb = (const uint4*)(ws + OFF_HB) + ((size_t)b * L + l0) * 64 + lane;

    float m = -1e30f, l = 0.f;
    float4 c4a = {0,0,0,0}, c4b = {0,0,0,0};

    #pragma unroll 2
    for (int i = 0; i < 32; i += 2){
        uint4 u0 = hb[(size_t)i * 64];
        uint4 u1 = hb[(size_t)(i + 1) * 64];
        float4 v0a, v0b, v1a, v1b;
        v0a.x = __uint_as_float(u0.x << 16); v0a.y = __uint_as_float(u0.x & 0xFFFF0000u);
        v0a.z = __uint_as_float(u0.y << 16); v0a.w = __uint_as_float(u0.y & 0xFFFF0000u);
        v0b.x = __uint_as_float(u0.z << 16); v0b.y = __uint_as_float(u0.z & 0xFFFF0000u);
        v0b.z = __uint_as_float(u0.w << 16); v0b.w = __uint_as_float(u0.w & 0xFFFF0000u);
        v1a.x = __uint_as_float(u1.x << 16); v1a.y = __uint_as_float(u1.x & 0xFFFF0000u);
        v1a.z = __uint_as_float(u1.y << 16); v1a.w = __uint_as_float(u1.y & 0xFFFF0000u);
        v1b.x = __uint_as_float(u1.z << 16); v1b.y = __uint_as_float(u1.z & 0xFFFF0000u);
        v1b.z = __uint_as_float(u1.w << 16); v1b.w = __uint_as_float(u1.w & 0xFFFF0000u);

        float dot0 = v0a.x*s4a.x + v0a.y*s4a.y + v0a.z*s4a.z + v0a.w*s4a.w
                   + v0b.x*s4b.x + v0b.y*s4b.y + v0b.z*s4b.z + v0b.w*s4b.w;
        float dot1 = v1a.x*s4a.x + v1a.y*s4a.y + v1a.z*s4a.z + v1a.w*s4a.w
                   + v1b.x*s4b.x + v1b.y*s4b.y + v1b.z*s4b.z + v1b.w*s4b.w;
        for (int off = 32; off; off >>= 1){
            dot0 += __shfl_xor(dot0, off, 64);
            dot1 += __shfl_xor(dot1, off, 64);
        }
        float sc0 = dot0 * __shfl(rnv, i)     * rssb;
        float sc1 = dot1 * __shfl(rnv, i + 1) * rssb;

        float nm = fmaxf(m, fmaxf(sc0, sc1));
        float al = __expf(m - nm);
        float p0 = __expf(sc0 - nm);
        float p1 = __expf(sc1 - nm);
        l = l * al + p0 + p1;
        c4a.x = c4a.x*al + p0*v0a.x + p1*v1a.x;
        c4a.y = c4a.y*al + p0*v0a.y + p1*v1a.y;
        c4a.z = c4a.z*al + p0*v0a.z + p1*v1a.z;
        c4a.w = c4a.w*al + p0*v0a.w + p1*v1a.w;
        c4b.x = c4b.x*al + p0*v0b.x + p1*v1b.x;
        c4b.y = c4b.y*al + p0*v0b.y + p1*v1b.y;
        c4b.z = c4b.z*al + p0*v0b.z + p1*v1b.z;
        c4b.w = c4b.w*al + p0*v0b.w + p1*v1b.w;
        m = nm;
    }

    // combine 4 waves in block
    __shared__ float lm[4], ll[4];
    __shared__ float lctx[4][512];
    *(float4*)&lctx[wave][8*lane]     = c4a;
    *(float4*)&lctx[wave][8*lane + 4] = c4b;
    if (lane == 0){ lm[wave] = m; ll[wave] = l; }
    __syncthreads();

    float M = fmaxf(fmaxf(lm[0], lm[1]), fmaxf(lm[2], lm[3]));
    float e0 = __expf(lm[0]-M), e1 = __expf(lm[1]-M);
    float e2 = __expf(lm[2]-M), e3 = __expf(lm[3]-M);
    int t = threadIdx.x;
    float* pc = ws + OFF_PCTX + ((size_t)b * S + chunk) * H;
    pc[t]       = lctx[0][t]*e0     + lctx[1][t]*e1     + lctx[2][t]*e2     + lctx[3][t]*e3;
    pc[t + 256] = lctx[0][t+256]*e0 + lctx[1][t+256]*e1 + lctx[2][t+256]*e2 + lctx[3][t+256]*e3;
    if (t == 0){
        ws[OFF_PM + b*S + chunk] = M;
        ws[OFF_PL + b*S + chunk] = ll[0]*e0 + ll[1]*e1 + ll[2]*e2 + ll[3]*e3;
    }
}

// ---- gates = x @ W_ih + h @ W_hh + b ; 1024 thr, 4-way K-split ----
__global__ __launch_bounds__(1024) void gates_k(const float* __restrict__ Wih,
                                                const float* __restrict__ Whh,
                                                const float* __restrict__ bias,
                                                float* __restrict__ ws){
    __shared__ float xs[8][512];
    __shared__ float hsh[8][512];
    __shared__ float4 red[3][8][32];
    int tid = threadIdx.x;
    int b0 = blockIdx.y * 8, n0 = blockIdx.x * 128;
    {
        int r = tid >> 7, c = (tid & 127) << 2;
        *(float4*)&xs[r][c]  = *(const float4*)(ws + OFF_X + (size_t)(b0 + r)*D + c);
        *(float4*)&hsh[r][c] = *(const float4*)(ws + OFF_H + (size_t)(b0 + r)*H + c);
    }
    __syncthreads();
    int nt = tid & 31, g = tid >> 5;
    int bi = g >> 2, kh = g & 3;
    int n = n0 + nt * 4;
    float4 acc = {0,0,0,0};
    const float* w1p = Wih + (size_t)(kh * 128) * NG + n;
    const float* w2p = Whh + (size_t)(kh * 128) * NG + n;
    const float* xr = &xs[bi][kh * 128];
    const float* hr = &hsh[bi][kh * 128];
    #pragma unroll 4
    for (int k = 0; k < 128; k++){
        float4 w1 = *(const float4*)(w1p + (size_t)k * NG);
        float4 w2 = *(const float4*)(w2p + (size_t)k * NG);
        float xv = xr[k], hv = hr[k];
        acc.x += xv*w1.x + hv*w2.x;
        acc.y += xv*w1.y + hv*w2.y;
        acc.z += xv*w1.z + hv*w2.z;
        acc.w += xv*w1.w + hv*w2.w;
    }
    if (kh) red[kh-1][bi][nt] = acc;
    __syncthreads();
    if (!kh){
        float4 r0 = red[0][bi][nt], r1 = red[1][bi][nt], r2 = red[2][bi][nt];
        float4 bb = *(const float4*)(bias + n);
        acc.x += r0.x + r1.x + r2.x + bb.x;
        acc.y += r0.y + r1.y + r2.y + bb.y;
        acc.z += r0.z + r1.z + r2.z + bb.z;
        acc.w += r0.w + r1.w + r2.w + bb.w;
        *(float4*)(ws + OFF_G + (size_t)(b0 + bi)*NG + n) = acc;
    }
}

// ---- fused: softmax-combine + LSTM cell + MLP head + output scatter ----
__global__ __launch_bounds__(256) void tail_k(const float* __restrict__ W1, const float* __restrict__ b1,
                                              const float* __restrict__ W2, const float* __restrict__ b2,
                                              float* __restrict__ ws, float* __restrict__ out, int st){
    int b = blockIdx.x, t = threadIdx.x;
    __shared__ float pm_s[S], pl_s[S];
    __shared__ float hl[512];
    __shared__ float part[4][64];
    __shared__ float t1[64];
    if (t < S){ pm_s[t] = ws[OFF_PM + b*S + t]; pl_s[t] = ws[OFF_PL + b*S + t]; }
    __syncthreads();
    float M = -1e30f;
    #pragma unroll
    for (int i = 0; i < S; i++) M = fmaxf(M, pm_s[i]);
    float e[S], Ls = 0.f;
    #pragma unroll
    for (int i = 0; i < S; i++){ e[i] = __expf(pm_s[i] - M); Ls += pl_s[i] * e[i]; }
    float inv = 1.0f / Ls;

    const float* g = ws + OFF_G + (size_t)b * NG;
    float csq = 0.f;
    for (int hh = t; hh < H; hh += 256){
        float cx = 0.f;
        #pragma unroll
        for (int i = 0; i < S; i++) cx += ws[OFF_PCTX + ((size_t)b*S + i)*H + hh] * e[i];
        float sn = ws[OFF_S + b*H + hh] + cx * inv;
        float gi = g[hh], gf = g[512 + hh], gg = g[1024 + hh], go = g[1536 + hh];
        float c  = sigf(gf) * sn + sigf(gi) * tanhf(gg);
        float hv = sigf(go) * tanhf(c);
        ws[OFF_S + b*H + hh] = c;
        ws[OFF_H + b*H + hh] = hv;
        hl[hh] = hv;
        csq += c * c;
    }
    float tot = block_sum256(csq);          // has an internal __syncthreads (hl visible after)
    if (t == 0) ws[OFF_SS + b] = tot;

    // MLP: t1 = leaky_relu(h@W1+b1)
    int j = t & 63, q = t >> 6;
    float a = 0.f;
    #pragma unroll 4
    for (int k = q*128; k < q*128 + 128; k++) a += hl[k] * W1[k*64 + j];
    part[q][j] = a;
    __syncthreads();
    if (t < 64){
        float v = part[0][t] + part[1][t] + part[2][t] + part[3][t] + b1[t];
        t1[t] = v > 0.f ? v : 0.01f * v;
    }
    __syncthreads();
    for (int d = t; d < D; d += 256){
        float a2 = b2[d];
        #pragma unroll
        for (int k = 0; k < 64; k++) a2 += t1[k] * W2[k*512 + d];
        ws[OFF_X + (size_t)b*D + d] = a2;
        int idx = st * D + d;
        out[(size_t)b * (D*T) + (size_t)(idx % T) * D + (idx / T)] = a2;
    }
}

extern "C" void kernel_launch(void* const* d_in, const int* in_sizes, int n_in,
                              void* d_out, int out_size, void* d_ws, size_t ws_size,
                              hipStream_t stream) {
    const float* batch = (const float*)d_in[0];
    const float* hid   = (const float*)d_in[1];
    const float* h0    = (const float*)d_in[2];
    const float* s0    = (const float*)d_in[3];
    const float* Wih   = (const float*)d_in[4];
    const float* Whh   = (const float*)d_in[5];
    const float* bl    = (const float*)d_in[6];
    const float* W1    = (const float*)d_in[7];
    const float* b1    = (const float*)d_in[8];
    const float* W2    = (const float*)d_in[9];
    const float* b2    = (const float*)d_in[10];
    float* out = (float*)d_out;
    float* ws  = (float*)d_ws;

    init_k<<<B, 256, 0, stream>>>(s0, h0, batch, ws);
    conv_k<<<(B*L)/4, 256, 0, stream>>>(hid, ws);
    for (int st = 0; st < T; st++){
        attn_part<<<B*S, 256, 0, stream>>>(ws);
        gates_k<<<dim3(16, 16), 1024, 0, stream>>>(Wih, Whh, bl, ws);
        tail_k<<<B, 256, 0, stream>>>(W1, b1, W2, b2, ws, out, st);
    }
}

// Round 3
// 1726.883 us; speedup vs baseline: 1.5720x; 1.2134x over previous
//
#include <hip/hip_runtime.h>
#include <math.h>

#define B 128
#define L 2048
#define H 512
#define D 512
#define NG 2048   // 4*H
#define T 10
#define S 16      // L-chunks per batch row for attention partials

// workspace layout (float offsets); ws_size = 2 GiB
#define OFF_S    ((size_t)0)        // c state (attention query), B*H
#define OFF_H    ((size_t)65536)    // hidden h, B*H
#define OFF_X    ((size_t)131072)   // current x, B*D
#define OFF_SS   ((size_t)196608)   // ||s||^2 per b, B
#define OFF_G    ((size_t)196736)   // gates, B*NG
#define OFF_PL   ((size_t)460928)   // partial l, B*S
#define OFF_PCTX ((size_t)462976)   // partial ctx, B*S*H
#define OFF_RN   ((size_t)1511552)  // 1/||h_l||, B*L
#define OFF_HB   ((size_t)1773696)  // bf16 copy of hid_states, B*L*H bf16

__device__ __forceinline__ float sigf(float x){ return 1.0f / (1.0f + __expf(-x)); }

__device__ __forceinline__ unsigned int b16r(float f){   // fp32 -> bf16 bits, RNE
    unsigned int u = __float_as_uint(f);
    return (u + 0x7FFFu + ((u >> 16) & 1u)) >> 16;
}
__device__ __forceinline__ unsigned int pack2(float lo, float hi){
    return b16r(lo) | (b16r(hi) << 16);
}

#define UNPK(u, f0, f1) { f0 = __uint_as_float((u) << 16); f1 = __uint_as_float((u) & 0xFFFF0000u); }

__device__ __forceinline__ float block_sum256(float v){
    for (int off = 32; off; off >>= 1) v += __shfl_xor(v, off, 64);
    __shared__ float r[4];
    int wave = threadIdx.x >> 6, lane = threadIdx.x & 63;
    if (lane == 0) r[wave] = v;
    __syncthreads();
    return r[0] + r[1] + r[2] + r[3];
}

// ---- init: s=s0, h=h0, x=batch, ss=||s0||^2 ----
__global__ void init_k(const float* __restrict__ s0, const float* __restrict__ h0,
                       const float* __restrict__ x0, float* __restrict__ ws){
    int b = blockIdx.x, t = threadIdx.x;
    float ssq = 0.f;
    for (int h = t; h < H; h += 256){
        float sv = s0[b*H + h];
        ws[OFF_S + b*H + h] = sv;
        ws[OFF_H + b*H + h] = h0[b*H + h];
        ssq += sv * sv;
    }
    for (int d = t; d < D; d += 256) ws[OFF_X + b*D + d] = x0[b*D + d];
    float tot = block_sum256(ssq);
    if (t == 0) ws[OFF_SS + b] = tot;
}

// ---- one-time: hid -> bf16 + rn = 1/||h_l||; 16-lane x 4-row layout ----
__global__ __launch_bounds__(256) void conv_k(const float* __restrict__ hid,
                                              float* __restrict__ ws){
    int wave = threadIdx.x >> 6, lane = threadIdx.x & 63;
    int g = lane & 15, r = lane >> 4;
    int row = blockIdx.x * 16 + wave * 4 + r;
    const float* src = hid + (size_t)row * H + g * 8;
    float f[32];
    #pragma unroll
    for (int cb = 0; cb < 4; cb++){
        float4 a = *(const float4*)(src + cb*128);
        float4 c = *(const float4*)(src + cb*128 + 4);
        f[cb*8+0]=a.x; f[cb*8+1]=a.y; f[cb*8+2]=a.z; f[cb*8+3]=a.w;
        f[cb*8+4]=c.x; f[cb*8+5]=c.y; f[cb*8+6]=c.z; f[cb*8+7]=c.w;
    }
    float sq = 0.f;
    #pragma unroll
    for (int k = 0; k < 32; k++) sq += f[k]*f[k];
    sq += __shfl_xor(sq, 1, 64);
    sq += __shfl_xor(sq, 2, 64);
    sq += __shfl_xor(sq, 4, 64);
    sq += __shfl_xor(sq, 8, 64);
    uint4* dst = (uint4*)(ws + OFF_HB) + (size_t)row * 64 + g;
    #pragma unroll
    for (int cb = 0; cb < 4; cb++){
        uint4 o;
        o.x = pack2(f[cb*8+0], f[cb*8+1]);
        o.y = pack2(f[cb*8+2], f[cb*8+3]);
        o.z = pack2(f[cb*8+4], f[cb*8+5]);
        o.w = pack2(f[cb*8+6], f[cb*8+7]);
        dst[cb*16] = o;
    }
    if (g == 0) ws[OFF_RN + row] = rsqrtf(sq);
}

// ---- attention partials: bounded scores -> no-max softmax; 16-lane x 4-row ----
__global__ __launch_bounds__(256) void attn_part(float* __restrict__ ws){
    int bid = blockIdx.x;
    int b = bid >> 4, chunk = bid & (S - 1);
    int wave = threadIdx.x >> 6, lane = threadIdx.x & 63;
    int g = lane & 15, r = lane >> 4;

    // preload s (pre-scaled by 1/||s||)
    const float* sb = ws + OFF_S + (size_t)b * H + g * 8;
    float rssb = rsqrtf(ws[OFF_SS + b]);
    float sf[32];
    #pragma unroll
    for (int cb = 0; cb < 4; cb++){
        float4 a = *(const float4*)(sb + cb*128);
        float4 c = *(const float4*)(sb + cb*128 + 4);
        sf[cb*8+0]=a.x*rssb; sf[cb*8+1]=a.y*rssb; sf[cb*8+2]=a.z*rssb; sf[cb*8+3]=a.w*rssb;
        sf[cb*8+4]=c.x*rssb; sf[cb*8+5]=c.y*rssb; sf[cb*8+6]=c.z*rssb; sf[cb*8+7]=c.w*rssb;
    }

    int l0w = chunk * 128 + wave * 32;
    const uint4* hbu = (const uint4*)(ws + OFF_HB) + ((size_t)b * L + l0w) * 64 + g;
    const float* rnp = ws + OFF_RN + (size_t)b * L + l0w;

    float ctx[32];
    #pragma unroll
    for (int k = 0; k < 32; k++) ctx[k] = 0.f;
    float lsum = 0.f;

    for (int it = 0; it < 8; it++){
        int ro = it*4 + r;
        const uint4* hr = hbu + (size_t)ro * 64;
        uint4 u0 = hr[0];
        uint4 u1 = hr[16];
        uint4 u2 = hr[32];
        uint4 u3 = hr[48];
        float rnv = rnp[ro];
        float f[32];
        UNPK(u0.x, f[0], f[1])   UNPK(u0.y, f[2], f[3])
        UNPK(u0.z, f[4], f[5])   UNPK(u0.w, f[6], f[7])
        UNPK(u1.x, f[8], f[9])   UNPK(u1.y, f[10], f[11])
        UNPK(u1.z, f[12], f[13]) UNPK(u1.w, f[14], f[15])
        UNPK(u2.x, f[16], f[17]) UNPK(u2.y, f[18], f[19])
        UNPK(u2.z, f[20], f[21]) UNPK(u2.w, f[22], f[23])
        UNPK(u3.x, f[24], f[25]) UNPK(u3.y, f[26], f[27])
        UNPK(u3.z, f[28], f[29]) UNPK(u3.w, f[30], f[31])
        float dot = 0.f;
        #pragma unroll
        for (int k = 0; k < 32; k++) dot += f[k] * sf[k];
        dot += __shfl_xor(dot, 1, 64);
        dot += __shfl_xor(dot, 2, 64);
        dot += __shfl_xor(dot, 4, 64);
        dot += __shfl_xor(dot, 8, 64);
        float p = __expf(dot * rnv);          // score in [-1,1] -> no max needed
        lsum += p;
        #pragma unroll
        for (int k = 0; k < 32; k++) ctx[k] += p * f[k];
    }

    // combine the 4 r-groups (once per 32 rows)
    #pragma unroll
    for (int k = 0; k < 32; k++){
        ctx[k] += __shfl_xor(ctx[k], 16, 64);
        ctx[k] += __shfl_xor(ctx[k], 32, 64);
    }
    lsum += __shfl_xor(lsum, 16, 64);
    lsum += __shfl_xor(lsum, 32, 64);

    __shared__ float lctx[4][512];
    __shared__ float ll[4];
    if (r == 0){
        #pragma unroll
        for (int cb = 0; cb < 4; cb++){
            float4 a = { ctx[cb*8+0], ctx[cb*8+1], ctx[cb*8+2], ctx[cb*8+3] };
            float4 c = { ctx[cb*8+4], ctx[cb*8+5], ctx[cb*8+6], ctx[cb*8+7] };
            *(float4*)&lctx[wave][cb*128 + g*8]     = a;
            *(float4*)&lctx[wave][cb*128 + g*8 + 4] = c;
        }
        if (g == 0) ll[wave] = lsum;
    }
    __syncthreads();
    int t = threadIdx.x;
    float* pc = ws + OFF_PCTX + ((size_t)b * S + chunk) * H;
    pc[t]       = lctx[0][t]     + lctx[1][t]     + lctx[2][t]     + lctx[3][t];
    pc[t + 256] = lctx[0][t+256] + lctx[1][t+256] + lctx[2][t+256] + lctx[3][t+256];
    if (t == 0) ws[OFF_PL + b*S + chunk] = ll[0] + ll[1] + ll[2] + ll[3];
}

// ---- gates = x @ W_ih + h @ W_hh + b ; 1024 thr, 4-way K-split ----
__global__ __launch_bounds__(1024) void gates_k(const float* __restrict__ Wih,
                                                const float* __restrict__ Whh,
                                                const float* __restrict__ bias,
                                                float* __restrict__ ws){
    __shared__ float xs[8][512];
    __shared__ float hsh[8][512];
    __shared__ float4 red[3][8][32];
    int tid = threadIdx.x;
    int b0 = blockIdx.y * 8, n0 = blockIdx.x * 128;
    {
        int r = tid >> 7, c = (tid & 127) << 2;
        *(float4*)&xs[r][c]  = *(const float4*)(ws + OFF_X + (size_t)(b0 + r)*D + c);
        *(float4*)&hsh[r][c] = *(const float4*)(ws + OFF_H + (size_t)(b0 + r)*H + c);
    }
    __syncthreads();
    int nt = tid & 31, g = tid >> 5;
    int bi = g >> 2, kh = g & 3;
    int n = n0 + nt * 4;
    float4 acc = {0,0,0,0};
    const float* w1p = Wih + (size_t)(kh * 128) * NG + n;
    const float* w2p = Whh + (size_t)(kh * 128) * NG + n;
    const float* xr = &xs[bi][kh * 128];
    const float* hr = &hsh[bi][kh * 128];
    #pragma unroll 4
    for (int k = 0; k < 128; k++){
        float4 w1 = *(const float4*)(w1p + (size_t)k * NG);
        float4 w2 = *(const float4*)(w2p + (size_t)k * NG);
        float xv = xr[k], hv = hr[k];
        acc.x += xv*w1.x + hv*w2.x;
        acc.y += xv*w1.y + hv*w2.y;
        acc.z += xv*w1.z + hv*w2.z;
        acc.w += xv*w1.w + hv*w2.w;
    }
    if (kh) red[kh-1][bi][nt] = acc;
    __syncthreads();
    if (!kh){
        float4 r0 = red[0][bi][nt], r1 = red[1][bi][nt], r2 = red[2][bi][nt];
        float4 bb = *(const float4*)(bias + n);
        acc.x += r0.x + r1.x + r2.x + bb.x;
        acc.y += r0.y + r1.y + r2.y + bb.y;
        acc.z += r0.z + r1.z + r2.z + bb.z;
        acc.w += r0.w + r1.w + r2.w + bb.w;
        *(float4*)(ws + OFF_G + (size_t)(b0 + bi)*NG + n) = acc;
    }
}

// ---- fused tail: combine + LSTM cell + MLP head + scatter; 512 threads ----
__global__ __launch_bounds__(512) void tail_k(const float* __restrict__ W1, const float* __restrict__ b1,
                                              const float* __restrict__ W2, const float* __restrict__ b2,
                                              float* __restrict__ ws, float* __restrict__ out, int st){
    int b = blockIdx.x, t = threadIdx.x;
    __shared__ float hl[512];
    __shared__ float part[8][64];
    __shared__ float t1[64];
    __shared__ float rr[8];

    float Ls = 0.f;
    #pragma unroll
    for (int i = 0; i < S; i++) Ls += ws[OFF_PL + b*S + i];
    float inv = 1.0f / Ls;

    float cx = 0.f;
    #pragma unroll
    for (int i = 0; i < S; i++) cx += ws[OFF_PCTX + ((size_t)b*S + i)*H + t];
    const float* g = ws + OFF_G + (size_t)b * NG;
    float sn = ws[OFF_S + b*H + t] + cx * inv;
    float gi = g[t], gf = g[512 + t], gg = g[1024 + t], go = g[1536 + t];
    float c  = sigf(gf) * sn + sigf(gi) * tanhf(gg);
    float hv = sigf(go) * tanhf(c);
    ws[OFF_S + b*H + t] = c;
    ws[OFF_H + b*H + t] = hv;
    hl[t] = hv;
    float csq = c * c;
    for (int off = 32; off; off >>= 1) csq += __shfl_xor(csq, off, 64);
    int wv = t >> 6, ln = t & 63;
    if (ln == 0) rr[wv] = csq;
    __syncthreads();
    if (t == 0){
        float s = 0.f;
        #pragma unroll
        for (int i = 0; i < 8; i++) s += rr[i];
        ws[OFF_SS + b] = s;
    }

    // MLP layer 1: 8-way k-split x 64 outputs
    int j = t & 63, q = t >> 6;
    float a = 0.f;
    #pragma unroll 4
    for (int k = q*64; k < q*64 + 64; k++) a += hl[k] * W1[k*64 + j];
    part[q][j] = a;
    __syncthreads();
    if (t < 64){
        float v = b1[t];
        #pragma unroll
        for (int i = 0; i < 8; i++) v += part[i][t];
        t1[t] = v > 0.f ? v : 0.01f * v;
    }
    __syncthreads();
    // MLP layer 2: one output per thread
    float a2 = b2[t];
    #pragma unroll
    for (int k = 0; k < 64; k++) a2 += t1[k] * W2[k*512 + t];
    ws[OFF_X + (size_t)b*D + t] = a2;
    int idx = st * D + t;
    out[(size_t)b * (D*T) + (size_t)(idx % T) * D + (idx / T)] = a2;
}

extern "C" void kernel_launch(void* const* d_in, const int* in_sizes, int n_in,
                              void* d_out, int out_size, void* d_ws, size_t ws_size,
                              hipStream_t stream) {
    const float* batch = (const float*)d_in[0];
    const float* hid   = (const float*)d_in[1];
    const float* h0    = (const float*)d_in[2];
    const float* s0    = (const float*)d_in[3];
    const float* Wih   = (const float*)d_in[4];
    const float* Whh   = (const float*)d_in[5];
    const float* bl    = (const float*)d_in[6];
    const float* W1    = (const float*)d_in[7];
    const float* b1    = (const float*)d_in[8];
    const float* W2    = (const float*)d_in[9];
    const float* b2    = (const float*)d_in[10];
    float* out = (float*)d_out;
    float* ws  = (float*)d_ws;

    init_k<<<B, 256, 0, stream>>>(s0, h0, batch, ws);
    conv_k<<<(B*L)/16, 256, 0, stream>>>(hid, ws);
    for (int st = 0; st < T; st++){
        attn_part<<<B*S, 256, 0, stream>>>(ws);
        gates_k<<<dim3(16, 16), 1024, 0, stream>>>(Wih, Whh, bl, ws);
        tail_k<<<B, 512, 0, stream>>>(W1, b1, W2, b2, ws, out, st);
    }
}